// Round 2
// baseline (583.789 us; speedup 1.0000x reference)
//
#include <hip/hip_runtime.h>
#include <hip/hip_bf16.h>
#include <stdint.h>
#include <math.h>

// Problem constants
#define NB 4
#define NT 2048
#define NC 2048
#define NH 16
#define HD 128
#define BT (NB*NT)   // 8192

typedef __attribute__((ext_vector_type(8))) short s16x8;
typedef __attribute__((ext_vector_type(4))) short s16x4;
typedef __attribute__((ext_vector_type(4))) float f32x4;

typedef __attribute__((address_space(1))) void as1_void;
typedef __attribute__((address_space(3))) void as3_void;

static __device__ __forceinline__ unsigned short f2bf(float f) {
  union { float f; uint32_t u; } v; v.f = f;
  return (unsigned short)((v.u + 0x7fffu + ((v.u >> 16) & 1u)) >> 16);
}
static __device__ __forceinline__ float bf2f(unsigned short u) {
  union { uint32_t u; float f; } v; v.u = ((uint32_t)u) << 16;
  return v.f;
}
static __device__ __forceinline__ void async16(unsigned short* lds, const unsigned short* g) {
  __builtin_amdgcn_global_load_lds((as1_void*)g, (as3_void*)lds, 16, 0, 0);
}
static __device__ __forceinline__ uint32_t lds_off(void* p) {
  return (uint32_t)(size_t)(as3_void*)p;
}

// ---------------- fp32 -> bf16 convert (vectorized, 8 elems/thread) ----------------
__global__ void k_convert_bf16(const float* __restrict__ in, unsigned short* __restrict__ out, int n8) {
  int i = blockIdx.x * blockDim.x + threadIdx.x;
  if (i >= n8) return;
  const float4* p = (const float4*)in + (size_t)i * 2;
  float4 a = p[0], b = p[1];
  union { unsigned short s[8]; uint4 u; } o;
  o.s[0] = f2bf(a.x); o.s[1] = f2bf(a.y); o.s[2] = f2bf(a.z); o.s[3] = f2bf(a.w);
  o.s[4] = f2bf(b.x); o.s[5] = f2bf(b.y); o.s[6] = f2bf(b.z); o.s[7] = f2bf(b.w);
  ((uint4*)out)[i] = o.u;
}

// ---------------- transpose + convert: W [K][N] fp32 -> WT [N][K] bf16 ----------------
__global__ void k_transpose_bf16(const float* __restrict__ W, unsigned short* __restrict__ WT, int K, int N) {
  __shared__ unsigned short tile[64][65];
  const int k0 = blockIdx.y * 64, n0 = blockIdx.x * 64;
  const int t = threadIdx.x;
  const int jj = t & 63, base_i = t >> 6;
  #pragma unroll
  for (int p = 0; p < 16; ++p) {
    int i = p * 4 + base_i;
    tile[i][jj] = f2bf(W[(size_t)(k0 + i) * N + n0 + jj]);
  }
  __syncthreads();
  #pragma unroll
  for (int p = 0; p < 16; ++p) {
    int j = p * 4 + base_i;
    WT[(size_t)(n0 + j) * K + k0 + jj] = tile[jj][j];
  }
}

// ---------------- RoPE in-place on Q,K [BH][T][D]; fold scale*log2e into Q ----------------
__global__ void k_rope(unsigned short* __restrict__ Q, unsigned short* __restrict__ Kb) {
  int idx = blockIdx.x * 256 + threadIdx.x;  // over BH*T*64
  int d = idx & 63;
  int tpos = (idx >> 6) & (NT - 1);
  int bh = idx >> 17;
  size_t o = ((size_t)bh * NT + tpos) * HD + d;
  float invf = exp2f(-(float)d * 0.2076205059304602f);  // log2(10000)/64
  float ang = (float)tpos * invf;
  float s, c;
  sincosf(ang, &s, &c);
  float q1 = bf2f(Q[o]),  q2 = bf2f(Q[o + 64]);
  float k1 = bf2f(Kb[o]), k2 = bf2f(Kb[o + 64]);
  const float qs = 0.08838834764831845f * 1.4426950408889634f;  // (1/sqrt(128))*log2e
  Q[o]       = f2bf((q1 * c - q2 * s) * qs);
  Q[o + 64]  = f2bf((q2 * c + q1 * s) * qs);
  Kb[o]      = f2bf(k1 * c - k2 * s);
  Kb[o + 64] = f2bf(k2 * c + k1 * s);
}

// ---------------- GEMM: C[M][N] = A[M][K] * Bt[N][K]^T + bias ----------------
// MODE 0: scatter bf16 into Q/K/V [B][H][T][D] (N=6144). MODE 1: fp32 row-major out.
template<int MODE>
__global__ __launch_bounds__(256, 2)
void k_gemm_bt(const unsigned short* __restrict__ A,
               const unsigned short* __restrict__ Bt,
               const float* __restrict__ bias,
               float* __restrict__ OutF,
               unsigned short* __restrict__ Qd,
               unsigned short* __restrict__ Kd,
               unsigned short* __restrict__ Vd,
               int M, int N, int K)
{
  __shared__ __align__(16) unsigned short Al[128 * 64];
  __shared__ __align__(16) unsigned short Bl[128 * 64];
  const int t = threadIdx.x;
  const int l = t & 63;
  const int wv = t >> 6;
  const int wm = wv >> 1, wn = wv & 1;
  const int bm = blockIdx.y * 128, bn = blockIdx.x * 128;
  const int lr = l & 15, lg = l >> 4;

  f32x4 acc[4][4];
  #pragma unroll
  for (int i = 0; i < 4; ++i)
    #pragma unroll
    for (int j = 0; j < 4; ++j)
      acc[i][j] = f32x4{0.f, 0.f, 0.f, 0.f};

  for (int k0 = 0; k0 < K; k0 += 64) {
    // stage 128x64 A-tile and B-tile; LDS linear dest, swizzled global source:
    // LDS 16B-chunk (row, c) holds logical k-chunk (c ^ (row&7))
    #pragma unroll
    for (int i = 0; i < 4; ++i) {
      const int Cc = i * 256 + t;          // 16B chunk id 0..1023
      const int row = Cc >> 3;
      const int kc = (Cc & 7) ^ (row & 7);
      async16(&Al[(i * 256 + (t & 192)) * 8], &A[(size_t)(bm + row) * K + k0 + kc * 8]);
      async16(&Bl[(i * 256 + (t & 192)) * 8], &Bt[(size_t)(bn + row) * K + k0 + kc * 8]);
    }
    __syncthreads();
    #pragma unroll
    for (int kk = 0; kk < 2; ++kk) {
      s16x8 af[4], bfr[4];
      #pragma unroll
      for (int mb = 0; mb < 4; ++mb) {
        const int row = wm * 64 + mb * 16 + lr;
        const int ch = (kk * 4 + lg) ^ (row & 7);
        af[mb] = *(const s16x8*)&Al[row * 64 + ch * 8];
      }
      #pragma unroll
      for (int nb = 0; nb < 4; ++nb) {
        const int row = wn * 64 + nb * 16 + lr;
        const int ch = (kk * 4 + lg) ^ (row & 7);
        bfr[nb] = *(const s16x8*)&Bl[row * 64 + ch * 8];
      }
      #pragma unroll
      for (int mb = 0; mb < 4; ++mb)
        #pragma unroll
        for (int nb = 0; nb < 4; ++nb)
          acc[mb][nb] = __builtin_amdgcn_mfma_f32_16x16x32_bf16(af[mb], bfr[nb], acc[mb][nb], 0, 0, 0);
    }
    __syncthreads();
  }

  // epilogue; C/D layout: col = lane&15, row = (lane>>4)*4 + reg  [m89-verified]
  #pragma unroll
  for (int mb = 0; mb < 4; ++mb) {
    #pragma unroll
    for (int nb = 0; nb < 4; ++nb) {
      const int col = bn + wn * 64 + nb * 16 + lr;
      const float bv = bias[col];
      #pragma unroll
      for (int r = 0; r < 4; ++r) {
        const int row = bm + wm * 64 + mb * 16 + lg * 4 + r;
        const float v = acc[mb][nb][r] + bv;
        if (MODE == 1) {
          OutF[(size_t)row * N + col] = v;
        } else {
          const int which = col >> 11;         // 0=q 1=k 2=v (uniform per block)
          const int cc = col & 2047;
          const int h = cc >> 7, d = cc & 127;
          const int b = row >> 11, tp = row & 2047;
          unsigned short* dst = (which == 0) ? Qd : (which == 1 ? Kd : Vd);
          dst[(((size_t)(b * NH + h)) * NT + tp) * HD + d] = f2bf(v);
        }
      }
    }
  }
}

// ---------------- flash attention: 4 waves x 16 q-rows, KV tile 64 ----------------
// swapped S^T = mfma(K, Q): lane owns q = lane&15; keys live at (lane>>4)*4+reg.
// PV: y^T = mfma(V^T via ds_read_b64_tr_b16 from subtiled V_lds, P^T from regs).
// tr_read semantics [m156/m162-consistent]: each lane does a contiguous 8B read at
// its own addr; the 16-lane group's 128B window is a row-major [4][16] bf16 matrix
// and lane l receives COLUMN (l&15): elem j = window[j*16 + (l&15)].
// => lane addr must be subtile_base + (l&15)*8 BYTES.
__global__ __launch_bounds__(256, 2)
void k_attn(const unsigned short* __restrict__ Q,
            const unsigned short* __restrict__ Kg,
            const unsigned short* __restrict__ Vg,
            unsigned short* __restrict__ Yatt)   // att [BT][NC] bf16
{
  __shared__ __align__(16) unsigned short Kl[64 * 128];  // [key][d], 16B-chunk-swizzled
  __shared__ __align__(16) unsigned short Vl[64 * 128];  // subtiled [key/4][d/16][4][16]
  const int qb = blockIdx.x;          // 0..31
  const int bh = blockIdx.y;          // 0..63
  const int b = bh >> 4, h = bh & 15;
  const int t = threadIdx.x, l = t & 63, wv = t >> 6;
  const int lr = l & 15, lg = l >> 4;
  const int q0w = qb * 64 + wv * 16;
  const int qrow = q0w + lr;
  const size_t hoff = (size_t)bh * NT * HD;
  const unsigned short* Qh = Q + hoff;
  const unsigned short* Kh = Kg + hoff;
  const unsigned short* Vh = Vg + hoff;

  s16x8 qf[4];  // Q[qrow][m*32 + lg*8 .. +8]
  #pragma unroll
  for (int m = 0; m < 4; ++m)
    qf[m] = *(const s16x8*)(Qh + (size_t)qrow * HD + m * 32 + lg * 8);

  f32x4 yt[8];  // y^T: 8 d-tiles of 16; lane: q=lr, d = n*16 + lg*4 + r
  #pragma unroll
  for (int n = 0; n < 8; ++n) yt[n] = f32x4{0.f, 0.f, 0.f, 0.f};
  float mrun = -1e30f, lrun = 0.f;
  const uint32_t vbase = lds_off(Vl);

  const int nkv = qb + 1;
  for (int kv = 0; kv < nkv; ++kv) {
    const int kv0 = kv * 64;
    #pragma unroll
    for (int i = 0; i < 4; ++i) {
      const int Cc = i * 256 + t;
      {  // K tile: row-major [64][128], 16B chunks swizzled with (row&7)
        const int krow = Cc >> 4;
        const int kc = (Cc & 15) ^ (krow & 7);
        async16(&Kl[(i * 256 + (t & 192)) * 8], &Kh[(size_t)(kv0 + krow) * HD + kc * 8]);
      }
      {  // V tile: subtile S = kq*8+dq holds [4 keys][16 d] row-major
        const int S = Cc >> 3, c8 = Cc & 7;
        const int kq = S >> 3, dq = S & 7;
        const int vk = kq * 4 + (c8 >> 1), vd = dq * 16 + (c8 & 1) * 8;
        async16(&Vl[(i * 256 + (t & 192)) * 8], &Vh[(size_t)(kv0 + vk) * HD + vd]);
      }
    }
    __syncthreads();

    // S^T tiles: 4 key-tiles of 16, k-dim = d (4 chunks of 32)
    f32x4 st[4];
    #pragma unroll
    for (int kt = 0; kt < 4; ++kt) {
      f32x4 a = f32x4{0.f, 0.f, 0.f, 0.f};
      const int krow = kt * 16 + lr;
      #pragma unroll
      for (int m = 0; m < 4; ++m) {
        const int ch = (m * 4 + lg) ^ (krow & 7);
        s16x8 kf = *(const s16x8*)&Kl[krow * 128 + ch * 8];
        a = __builtin_amdgcn_mfma_f32_16x16x32_bf16(kf, qf[m], a, 0, 0, 0);
      }
      st[kt] = a;
    }

    // causal mask (only needed near diagonal)
    if (kv0 + 63 > q0w) {
      #pragma unroll
      for (int kt = 0; kt < 4; ++kt)
        #pragma unroll
        for (int r = 0; r < 4; ++r) {
          const int key = kv0 + kt * 16 + lg * 4 + r;
          if (key > qrow) st[kt][r] = -3.0e38f;
        }
    }

    // online softmax (S already scaled by 1/sqrt(D)*log2e via Q)
    float tm = -3.0e38f;
    #pragma unroll
    for (int kt = 0; kt < 4; ++kt)
      #pragma unroll
      for (int r = 0; r < 4; ++r) tm = fmaxf(tm, st[kt][r]);
    tm = fmaxf(tm, __shfl_xor(tm, 16));
    tm = fmaxf(tm, __shfl_xor(tm, 32));
    const float mnew = fmaxf(mrun, tm);
    const float fsc = exp2f(mrun - mnew);
    mrun = mnew;
    lrun *= fsc;
    #pragma unroll
    for (int n = 0; n < 8; ++n)
      #pragma unroll
      for (int r = 0; r < 4; ++r) yt[n][r] *= fsc;

    unsigned short pb[16];
    float psum = 0.f;
    #pragma unroll
    for (int kt = 0; kt < 4; ++kt)
      #pragma unroll
      for (int r = 0; r < 4; ++r) {
        const float p = exp2f(st[kt][r] - mnew);
        psum += p;
        pb[kt * 4 + r] = f2bf(p);
      }
    lrun += psum;

    // pack P^T frags: element j of k-group gk = key gk*32 + 16*(j>>2) + lg*4 + (j&3)
    s16x8 pf[2];
    #pragma unroll
    for (int gk = 0; gk < 2; ++gk)
      #pragma unroll
      for (int j = 0; j < 8; ++j)
        pf[gk][j] = (short)pb[(gk * 2 + (j >> 2)) * 4 + (j & 3)];

    // PV: yt[n] += V^T_frag * pf[gk]; V^T frag elem j = V[key gk*32+16*(j>>2)+lg*4+(j&3)][n*16+lr]
    #pragma unroll
    for (int gk = 0; gk < 2; ++gk) {
      s16x4 va[8], vb2[8];
      #pragma unroll
      for (int n = 0; n < 8; ++n) {
        // subtile S = (kq = gk*8+lg)*8 + (dq = n); lane addr = S*128 + lr*8 bytes
        const uint32_t a0 = vbase + ((uint32_t)((gk * 8 + lg) * 8 + n)) * 128 + (uint32_t)lr * 8;
        asm volatile("ds_read_b64_tr_b16 %0, %1" : "=v"(va[n])  : "v"(a0));
        asm volatile("ds_read_b64_tr_b16 %0, %1" : "=v"(vb2[n]) : "v"(a0 + 4096));
      }
      asm volatile("s_waitcnt lgkmcnt(0)" ::: "memory");
      __builtin_amdgcn_sched_barrier(0);
      #pragma unroll
      for (int n = 0; n < 8; ++n) {
        s16x8 vf;
        vf[0] = va[n][0];  vf[1] = va[n][1];  vf[2] = va[n][2];  vf[3] = va[n][3];
        vf[4] = vb2[n][0]; vf[5] = vb2[n][1]; vf[6] = vb2[n][2]; vf[7] = vb2[n][3];
        yt[n] = __builtin_amdgcn_mfma_f32_16x16x32_bf16(vf, pf[gk], yt[n], 0, 0, 0);
      }
    }
    __syncthreads();
  }

  // finalize: reduce l across the 4 lane-groups, scale, write att row
  lrun += __shfl_xor(lrun, 16);
  lrun += __shfl_xor(lrun, 32);
  const float inv = 1.f / lrun;
  unsigned short* yrow = Yatt + (size_t)(b * NT + q0w + lr) * NC + h * HD;
  #pragma unroll
  for (int n = 0; n < 8; ++n)
    #pragma unroll
    for (int r = 0; r < 4; ++r)
      yrow[n * 16 + lg * 4 + r] = f2bf(yt[n][r] * inv);
}

extern "C" void kernel_launch(void* const* d_in, const int* in_sizes, int n_in,
                              void* d_out, int out_size, void* d_ws, size_t ws_size,
                              hipStream_t stream) {
  (void)in_sizes; (void)n_in; (void)out_size; (void)ws_size;
  const float* x     = (const float*)d_in[0];
  const float* Wqkv  = (const float*)d_in[1];
  const float* bqkv  = (const float*)d_in[2];
  const float* Wproj = (const float*)d_in[3];
  const float* bproj = (const float*)d_in[4];
  float* out = (float*)d_out;
  char* ws = (char*)d_ws;

  // workspace layout (160 MB total)
  unsigned short* xb     = (unsigned short*)(ws);               // 32MB  [BT][NC] bf16
  unsigned short* WqkvT  = (unsigned short*)(ws + 33554432);    // 24MB  [6144][2048]
  unsigned short* WprojT = (unsigned short*)(ws + 58720256);    // 8MB   [2048][2048]
  unsigned short* Qb     = (unsigned short*)(ws + 67108864);    // 32MB  [BH][T][D]
  unsigned short* Kb     = (unsigned short*)(ws + 100663296);   // 32MB
  unsigned short* Vb     = (unsigned short*)(ws + 134217728);   // 32MB
  unsigned short* att    = xb;  // reuse (xb dead after GEMM1)

  k_convert_bf16<<<dim3(8192), dim3(256), 0, stream>>>(x, xb, BT * NC / 8);
  k_transpose_bf16<<<dim3(96, 32), dim3(256), 0, stream>>>(Wqkv, WqkvT, NC, 3 * NC);
  k_transpose_bf16<<<dim3(32, 32), dim3(256), 0, stream>>>(Wproj, WprojT, NC, NC);
  k_gemm_bt<0><<<dim3(48, 64), dim3(256), 0, stream>>>(xb, WqkvT, bqkv, nullptr, Qb, Kb, Vb, BT, 3 * NC, NC);
  k_rope<<<dim3(32768), dim3(256), 0, stream>>>(Qb, Kb);
  k_attn<<<dim3(32, 64), dim3(256), 0, stream>>>(Qb, Kb, Vb, att);
  k_gemm_bt<1><<<dim3(16, 64), dim3(256), 0, stream>>>(att, WprojT, bproj, out, nullptr, nullptr, nullptr, BT, NC, NC);
}